// Round 8
// baseline (4802.080 us; speedup 1.0000x reference)
//
#include <hip/hip_runtime.h>
#include <math.h>

// B=4, DIM=192, H=W=64, L=4096, HEADS=6. All f32 buffers.
// Key structural fact: attention_ca's output (fmap1) is consumed ONLY by the
// routing (batch 0). So stage A is computed for b=0 only, entirely in f64,
// and bins are ranked directly (softmax is monotone => same top-k).
// Back half (experts/exout/kv/q/final attention) identical to prior rounds.

struct ExPtrs { const float* w[12]; const float* b[12]; };

// ================= routing chain, b=0, all f64 =================

// xpool64[j*4096+l] = mean_r T[0, 4j+r, l]. grid (48), 256 thr.
__global__ void pool64_kernel(const float* __restrict__ T, double* __restrict__ xp) {
    int j = blockIdx.x;
    for (int l = threadIdx.x; l < 4096; l += 256) {
        const float* t = T + ((size_t)(4 * j)) * 4096 + l;
        double s = (double)t[0] + (double)t[4096] + (double)t[2 * 4096] + (double)t[3 * 4096];
        xp[(size_t)j * 4096 + l] = 0.25 * s;
    }
}

// l2norm f32 row -> f64 row. grid = rows.
__global__ void norm64_f32_kernel(const float* __restrict__ src, double* __restrict__ dst) {
    size_t off = (size_t)blockIdx.x * 4096;
    double acc = 0.0;
    for (int i = threadIdx.x; i < 4096; i += 256) { double v = src[off + i]; acc += v * v; }
    __shared__ double red[256];
    red[threadIdx.x] = acc; __syncthreads();
    for (int st = 128; st > 0; st >>= 1) {
        if (threadIdx.x < st) red[threadIdx.x] += red[threadIdx.x + st];
        __syncthreads();
    }
    double scale = 1.0 / fmax(sqrt(red[0]), 1e-12);
    for (int i = threadIdx.x; i < 4096; i += 256) dst[off + i] = src[off + i] * scale;
}

// l2norm f64 row in place. grid = rows.
__global__ void norm64_f64_kernel(double* __restrict__ buf) {
    size_t off = (size_t)blockIdx.x * 4096;
    double acc = 0.0;
    for (int i = threadIdx.x; i < 4096; i += 256) { double v = buf[off + i]; acc += v * v; }
    __shared__ double red[256];
    red[threadIdx.x] = acc; __syncthreads();
    for (int st = 128; st > 0; st >>= 1) {
        if (threadIdx.x < st) red[threadIdx.x] += red[threadIdx.x + st];
        __syncthreads();
    }
    double scale = 1.0 / fmax(sqrt(red[0]), 1e-12);
    for (int i = threadIdx.x; i < 4096; i += 256) buf[off + i] *= scale;
}

// Stage-A logits+softmax (b=0): S[c,d] = qn64[hh*32+c]·kn64[hh*8+d]; softmax over
// the 8 base logits (exact identity with the 4x-tiled 32-softmax). grid (6), 256.
__global__ void attnA64_kernel(const double* __restrict__ qn, const double* __restrict__ kn,
                               double* __restrict__ A) {
    int hh = blockIdx.x;
    int t = threadIdx.x;
    int c = t >> 3, d = t & 7;
    const double* q = qn + ((size_t)(hh * 32 + c)) * 4096;
    const double* k = kn + ((size_t)(hh * 8 + d)) * 4096;
    double acc = 0.0;
    for (int i = 0; i < 4096; ++i) acc += q[i] * k[i];
    __shared__ double S[32][8];
    S[c][d] = acc;
    __syncthreads();
    if (t < 32) {
        double mx = -1e300;
        for (int j = 0; j < 8; ++j) mx = fmax(mx, S[t][j]);
        double e[8], sum = 0.0;
        for (int j = 0; j < 8; ++j) { e[j] = exp(S[t][j] - mx); sum += e[j]; }
        double inv = 1.0 / sum;
        for (int j = 0; j < 8; ++j) A[((size_t)(hh * 32 + t)) * 8 + j] = e[j] * inv;
    }
}

// aout64[ch*4096+l] = sum_d A[ch*8+d] * kn64[(hh*8+d)*4096+l]. grid (16,192).
__global__ void aout64_kernel(const double* __restrict__ A, const double* __restrict__ kn,
                              double* __restrict__ out) {
    int l = blockIdx.x * 256 + threadIdx.x;
    int ch = blockIdx.y;
    int hh = ch >> 5;
    const double* a = A + (size_t)ch * 8;
    const double* v = kn + ((size_t)(hh * 8)) * 4096 + l;
    double acc = 0.0;
    #pragma unroll
    for (int d = 0; d < 8; ++d) acc += a[d] * v[(size_t)d * 4096];
    out[(size_t)ch * 4096 + l] = acc;
}

// fm64[oc*4096+l] = sum_ic ca1[oc*192+ic] * aout64[ic*4096+l]. grid (16,192).
__global__ void fm64_kernel(const double* __restrict__ in, const float* __restrict__ w,
                            double* __restrict__ out) {
    int l = blockIdx.x * 256 + threadIdx.x;
    int oc = blockIdx.y;
    const double* src = in + l;
    const float* wr = w + (size_t)oc * 192;
    double acc = 0.0;
    for (int ic = 0; ic < 192; ++ic) acc += (double)wr[ic] * src[(size_t)ic * 4096];
    out[(size_t)oc * 4096 + l] = acc;
}

// m64[x] = mean over c<192,y<64 of fm64[c*4096+y*64+x]. grid (64).
__global__ void meanx64_kernel(const double* __restrict__ fm, double* __restrict__ m) {
    int x = blockIdx.x;
    double acc = 0.0;
    for (int t = threadIdx.x; t < 192 * 64; t += 256) {
        int c = t >> 6, y = t & 63;
        acc += fm[(size_t)c * 4096 + y * 64 + x];
    }
    __shared__ double red[256];
    red[threadIdx.x] = acc; __syncthreads();
    for (int st = 128; st > 0; st >>= 1) {
        if (threadIdx.x < st) red[threadIdx.x] += red[threadIdx.x + st];
        __syncthreads();
    }
    if (threadIdx.x == 0) m[x] = red[0] / (192.0 * 64.0);
}

// bins (f64) ranked directly (softmax monotone). Ties: lowest index first.
__global__ void route64_kernel(const double* __restrict__ m, int* __restrict__ idx) {
    if (threadIdx.x != 0) return;
    double bins[12];
    for (int i = 0; i < 12; ++i) {
        int st = (i * 64) / 12;
        int en = ((i + 1) * 64 + 11) / 12;   // ceil
        double s = 0.0;
        for (int j = st; j < en; ++j) s += m[j];
        bins[i] = s / (double)(en - st);
    }
    bool used[12] = {};
    for (int s = 0; s < 4; ++s) {
        int best = 0; double bv = -1e300;
        for (int j = 0; j < 12; ++j)
            if (!used[j] && bins[j] > bv) { best = j; bv = bins[j]; }
        used[best] = true;
        idx[s] = best;
    }
}

// ================= back half (f32, unchanged) =================

__global__ void rownorm_kernel(const float* __restrict__ src, float* __restrict__ dst) {
    size_t off = (size_t)blockIdx.x * 4096;
    const float* s = src + off;
    float acc = 0.f;
    for (int i = threadIdx.x; i < 4096; i += 256) { float v = s[i]; acc += v * v; }
    __shared__ float red[256];
    red[threadIdx.x] = acc; __syncthreads();
    for (int st = 128; st > 0; st >>= 1) {
        if (threadIdx.x < st) red[threadIdx.x] += red[threadIdx.x + st];
        __syncthreads();
    }
    float scale = 1.0f / fmaxf(sqrtf(red[0]), 1e-12f);
    float* d = dst + off;
    for (int i = threadIdx.x; i < 4096; i += 256) d[i] = s[i] * scale;
}

__global__ void conv1x1_kernel(const float* __restrict__ in, const float* __restrict__ w,
                               const float* __restrict__ bias, float* __restrict__ out,
                               int Cin, int Cout) {
    __shared__ float sw[16 * 192];
    int tid = threadIdx.x;
    int l = blockIdx.x * 256 + tid;
    int og = blockIdx.y, b = blockIdx.z;
    for (int t = tid; t < 16 * Cin; t += 256) {
        int u = t / Cin, i = t - u * Cin;
        sw[t] = w[(size_t)(og * 16 + u) * Cin + i];
    }
    __syncthreads();
    float acc[16];
    #pragma unroll
    for (int u = 0; u < 16; ++u) acc[u] = bias ? bias[og * 16 + u] : 0.f;
    const float* src = in + (size_t)b * Cin * 4096 + l;
    for (int i = 0; i < Cin; ++i) {
        float xv = src[(size_t)i * 4096];
        #pragma unroll
        for (int u = 0; u < 16; ++u) acc[u] += sw[u * Cin + i] * xv;
    }
    float* dst = out + ((size_t)(b * Cout) + og * 16) * 4096 + l;
    #pragma unroll
    for (int u = 0; u < 16; ++u) dst[(size_t)u * 4096] = acc[u];
}

__global__ void expert_dense_kernel(const float* __restrict__ I, ExPtrs ep,
                                    const int* __restrict__ idx, int slot,
                                    float* __restrict__ E) {
    int j = idx[slot];
    j = j < 0 ? 0 : (j > 11 ? 11 : j);
    if (j >= 6) return;
    int K = 1 + 2 * (j % 3), pad = j % 3;
    const float* w = ep.w[j];
    const float* bias = ep.b[j];
    __shared__ float sw[16 * 192];
    int tid = threadIdx.x;
    int x = tid & 63, ty = tid >> 6;
    int y = blockIdx.x * 4 + ty;
    int og = blockIdx.y, b = blockIdx.z;
    float acc[16];
    #pragma unroll
    for (int u = 0; u < 16; ++u) acc[u] = bias[og * 16 + u];
    for (int ky = 0; ky < K; ++ky) {
        for (int kx = 0; kx < K; ++kx) {
            __syncthreads();
            for (int t = tid; t < 16 * 192; t += 256) {
                int u = t / 192, i = t - u * 192;
                sw[t] = w[(((size_t)(og * 16 + u) * 192 + i) * K + ky) * K + kx];
            }
            __syncthreads();
            int yy = y + ky - pad, xx = x + kx - pad;
            if (yy >= 0 && yy < 64 && xx >= 0 && xx < 64) {
                const float* src = I + (size_t)b * 192 * 4096 + yy * 64 + xx;
                for (int i = 0; i < 192; ++i) {
                    float xv = src[(size_t)i * 4096];
                    #pragma unroll
                    for (int u = 0; u < 16; ++u) acc[u] += sw[u * 192 + i] * xv;
                }
            }
        }
    }
    float* dst = E + ((size_t)(b * 192 + og * 16)) * 4096 + y * 64 + x;
    #pragma unroll
    for (int u = 0; u < 16; ++u) dst[(size_t)u * 4096] = acc[u];
}

__global__ void expert_dw_kernel(const float* __restrict__ I, ExPtrs ep,
                                 const int* __restrict__ idx, int slot,
                                 float* __restrict__ E) {
    int j = idx[slot];
    j = j < 0 ? 0 : (j > 11 ? 11 : j);
    if (j < 6) return;
    int K = 1 + 2 * (j % 3), pad = j % 3;
    const float* w = ep.w[j];
    const float* bias = ep.b[j];
    int l = blockIdx.x * 256 + threadIdx.x;
    int ch = blockIdx.y, b = blockIdx.z;
    int y = l >> 6, x = l & 63;
    float acc = bias[ch];
    const float* src = I + ((size_t)(b * 192 + ch)) * 4096;
    for (int ky = 0; ky < K; ++ky)
        for (int kx = 0; kx < K; ++kx) {
            int yy = y + ky - pad, xx = x + kx - pad;
            if (yy >= 0 && yy < 64 && xx >= 0 && xx < 64)
                acc += w[((size_t)ch * K + ky) * K + kx] * src[yy * 64 + xx];
        }
    E[((size_t)(b * 192 + ch)) * 4096 + l] = acc;
}

__global__ void exout_accum_kernel(const float* __restrict__ E, const float* __restrict__ w,
                                   const float* __restrict__ bias, float* __restrict__ out,
                                   int slot) {
    __shared__ float sw[16 * 192];
    int tid = threadIdx.x;
    int x = tid & 63, ty = tid >> 6;
    int y = blockIdx.x * 4 + ty;
    int og = blockIdx.y, b = blockIdx.z;
    float* dst = out + ((size_t)(b * 192 + og * 16)) * 4096 + y * 64 + x;
    float acc[16];
    #pragma unroll
    for (int u = 0; u < 16; ++u)
        acc[u] = (slot == 0) ? bias[og * 16 + u] : dst[(size_t)u * 4096];
    for (int ky = 0; ky < 3; ++ky) {
        int yy = y + ky - 1;
        for (int kx = 0; kx < 3; ++kx) {
            int xx = x + kx - 1;
            __syncthreads();
            for (int t = tid; t < 16 * 192; t += 256) {
                int u = t / 192, i = t - u * 192;
                sw[t] = w[((size_t)(og * 16 + u) * 768 + slot * 192 + i) * 9 + ky * 3 + kx];
            }
            __syncthreads();
            if (yy >= 0 && yy < 64 && xx >= 0 && xx < 64) {
                const float* src = E + ((size_t)(b * 192)) * 4096 + yy * 64 + xx;
                for (int i = 0; i < 192; ++i) {
                    float xv = src[(size_t)i * 4096];
                    #pragma unroll
                    for (int u = 0; u < 16; ++u) acc[u] += sw[u * 192 + i] * xv;
                }
            }
        }
    }
    #pragma unroll
    for (int u = 0; u < 16; ++u) dst[(size_t)u * 4096] = acc[u];
}

__global__ void dwconv_kernel(const float* __restrict__ in, const float* __restrict__ w,
                              float* __restrict__ out) {
    int l = blockIdx.x * 256 + threadIdx.x;
    int ch = blockIdx.y, b = blockIdx.z;
    int y = l >> 6, x = l & 63;
    const float* src = in + ((size_t)(b * 192 + ch)) * 4096;
    const float* wk = w + ch * 9;
    float acc = 0.f;
    #pragma unroll
    for (int ky = 0; ky < 3; ++ky)
        #pragma unroll
        for (int kx = 0; kx < 3; ++kx) {
            int yy = y + ky - 1, xx = x + kx - 1;
            if (yy >= 0 && yy < 64 && xx >= 0 && xx < 64)
                acc += wk[ky * 3 + kx] * src[yy * 64 + xx];
        }
    out[((size_t)(b * 192 + ch)) * 4096 + l] = acc;
}

__global__ void attnF_s_kernel(const float* __restrict__ qn, const float* __restrict__ kn,
                               const float* __restrict__ temp, float* __restrict__ AF) {
    int blk = blockIdx.x;
    int b = blk / 6, hh = blk % 6;
    __shared__ float S[32][32];
    float tmp = temp[hh];
    for (int p = threadIdx.x; p < 1024; p += 256) {
        int c = p >> 5, d = p & 31;
        const float* q = qn + ((size_t)(b * 192 + hh * 32 + c)) * 4096;
        const float* k = kn + ((size_t)(b * 192 + hh * 32 + d)) * 4096;
        float acc = 0.f;
        #pragma unroll 4
        for (int i = 0; i < 4096; ++i) acc += q[i] * k[i];
        S[c][d] = acc * tmp;
    }
    __syncthreads();
    if (threadIdx.x < 32) {
        int c = threadIdx.x;
        float mx = -1e30f;
        for (int d = 0; d < 32; ++d) mx = fmaxf(mx, S[c][d]);
        float sum = 0.f;
        for (int d = 0; d < 32; ++d) { float e = expf(S[c][d] - mx); S[c][d] = e; sum += e; }
        float inv = 1.f / sum;
        for (int d = 0; d < 32; ++d) AF[((size_t)(blk * 32 + c)) * 32 + d] = S[c][d] * inv;
    }
}

__global__ void attnF_out_kernel(const float* __restrict__ AF, const float* __restrict__ v,
                                 float* __restrict__ out) {
    int l = blockIdx.x * 256 + threadIdx.x;
    int ch = blockIdx.y, b = blockIdx.z;
    int hh = ch >> 5, c = ch & 31;
    const float* a = AF + ((size_t)((b * 6 + hh) * 32 + c)) * 32;
    const float* vp = v + ((size_t)(b * 192 + hh * 32)) * 4096 + l;
    float acc = 0.f;
    #pragma unroll
    for (int d = 0; d < 32; ++d) acc += a[d] * vp[(size_t)d * 4096];
    out[((size_t)(b * 192 + ch)) * 4096 + l] = acc;
}

// ---------------- launch ----------------
extern "C" void kernel_launch(void* const* d_in, const int* in_sizes, int n_in,
                              void* d_out, int out_size, void* d_ws, size_t ws_size,
                              hipStream_t stream) {
    const float* I    = (const float*)d_in[0];
    const float* T    = (const float*)d_in[1];
    const float* temp = (const float*)d_in[2];
    const float* ca1  = (const float*)d_in[3];
    const float* exow = (const float*)d_in[4];
    const float* exob = (const float*)d_in[5];
    const float* kvw  = (const float*)d_in[6];
    const float* kvdw = (const float*)d_in[7];
    const float* qdw  = (const float*)d_in[8];
    const float* projw= (const float*)d_in[9];
    ExPtrs ep;
    for (int j = 0; j < 12; ++j) {               // dict order: interleaved
        ep.w[j] = (const float*)d_in[10 + 2 * j];
        ep.b[j] = (const float*)d_in[11 + 2 * j];
    }

    // Arena: AF(24576 f32) | idxb | R0 | R1 | R2 (3,145,728 f32 each) | A64,m64 (f64)
    float* ws   = (float*)d_ws;
    float* AF   = ws;                 // 24576
    int*   idxb = (int*)(ws + 24576); // 4
    float* R0   = ws + 32768;
    float* R1   = R0 + 3145728;
    float* R2   = R1 + 3145728;
    double* dbase   = (double*)(R2 + 3145728);   // 8-aligned (byte offset 37,879,808)
    double* A64     = dbase;                     // 1536
    double* m64     = dbase + 1536;              // 64
    // f64 stage-A buffers live inside R0/R1 (dead before back half starts)
    double* xpool64 = (double*)R0;               // 196608
    double* kn64    = xpool64 + 196608;          // 196608
    double* qn64    = kn64 + 196608;             // 786432  (total 9.44MB <= R0)
    double* aout64  = (double*)R1;               // 786432
    double* fm64    = aout64 + 786432;           // 786432  (total = R1 exactly)
    float* out  = (float*)d_out;

    dim3 g(16, 192, 4), g16(16, 12, 4);

    // ---- Routing chain (b=0, f64) ----
    pool64_kernel<<<48, 256, 0, stream>>>(T, xpool64);
    norm64_f32_kernel<<<192, 256, 0, stream>>>(I, qn64);     // q rows, b=0
    norm64_f64_kernel<<<48, 256, 0, stream>>>(xpool64);      // becomes kn64 source
    // normalized xpool64 IS kn64's content; copy-free: use xpool64 as kn
    attnA64_kernel<<<6, 256, 0, stream>>>(qn64, xpool64, A64);
    aout64_kernel<<<dim3(16, 192), 256, 0, stream>>>(A64, xpool64, aout64);
    fm64_kernel<<<dim3(16, 192), 256, 0, stream>>>(aout64, ca1, fm64);
    meanx64_kernel<<<64, 256, 0, stream>>>(fm64, m64);
    route64_kernel<<<1, 64, 0, stream>>>(m64, idxb);
    (void)kn64;

    // ---- Experts: E=R2, fmap2 accumulates in R1 (stage-A f64 buffers dead) ----
    for (int s = 0; s < 4; ++s) {
        expert_dense_kernel<<<g16, 256, 0, stream>>>(I, ep, idxb, s, R2);
        expert_dw_kernel<<<g, 256, 0, stream>>>(I, ep, idxb, s, R2);
        exout_accum_kernel<<<g16, 256, 0, stream>>>(R2, exow, exob, R1, s);
    }

    // ---- kv k-half ----
    conv1x1_kernel<<<g16, 256, 0, stream>>>(R1, kvw, nullptr, R0, 192, 192);
    dwconv_kernel<<<g, 256, 0, stream>>>(R0, kvdw, R2);
    rownorm_kernel<<<768, 256, 0, stream>>>(R2, R2);          // kn
    // ---- q ----
    dwconv_kernel<<<g, 256, 0, stream>>>(R1, qdw, R0);
    rownorm_kernel<<<768, 256, 0, stream>>>(R0, R0);          // qn
    attnF_s_kernel<<<24, 256, 0, stream>>>(R0, R2, temp, AF);
    // ---- kv v-half ----
    conv1x1_kernel<<<g16, 256, 0, stream>>>(R1, kvw + 192 * 192, nullptr, R0, 192, 192);
    dwconv_kernel<<<g, 256, 0, stream>>>(R0, kvdw + 192 * 9, R2);  // v

    attnF_out_kernel<<<g, 256, 0, stream>>>(AF, R2, R1);
    conv1x1_kernel<<<g16, 256, 0, stream>>>(R1, projw, nullptr, out, 192, 192);
}

// Round 9
// 3967.722 us; speedup vs baseline: 1.2103x; 1.2103x over previous
//
#include <hip/hip_runtime.h>
#include <math.h>

// B=4, DIM=192, H=W=64, L=4096, HEADS=6. f32 buffers; f64 routing chain (b=0).
// Big convs = register-tiled implicit GEMM, 8oc x 4px per thread, weights
// pre-transposed to [kk][og8][ic][8] and read as wave-uniform float4 pairs.

struct ExPtrs { const float* w[12]; const float* b[12]; };
struct DPtrs  { const float* wt[6]; const float* bias[6]; };

// ---------------- weight transpose: w[(oc*IC+ic)*KK*KK+kk] -> wt[((kk*OC8+og8)*IC+ic)*8+u]
__global__ void wtr_kernel(const float* __restrict__ w, float* __restrict__ wt,
                           int OC8, int IC, int KK) {
    int n = KK * KK * OC8 * IC * 8;
    for (int o = blockIdx.x * 256 + threadIdx.x; o < n; o += gridDim.x * 256) {
        int u = o & 7;
        int t1 = o >> 3;
        int ic = t1 % IC;
        int t2 = t1 / IC;
        int og8 = t2 % OC8;
        int kk = t2 / OC8;
        wt[o] = w[(((size_t)(og8 * 8 + u)) * IC + ic) * (KK * KK) + kk];
    }
}

// ================= routing chain, b=0, all f64 (unchanged from r8) =================

__global__ void pool64_kernel(const float* __restrict__ T, double* __restrict__ xp) {
    int j = blockIdx.x;
    for (int l = threadIdx.x; l < 4096; l += 256) {
        const float* t = T + ((size_t)(4 * j)) * 4096 + l;
        double s = (double)t[0] + (double)t[4096] + (double)t[2 * 4096] + (double)t[3 * 4096];
        xp[(size_t)j * 4096 + l] = 0.25 * s;
    }
}

__global__ void norm64_f32_kernel(const float* __restrict__ src, double* __restrict__ dst) {
    size_t off = (size_t)blockIdx.x * 4096;
    double acc = 0.0;
    for (int i = threadIdx.x; i < 4096; i += 256) { double v = src[off + i]; acc += v * v; }
    __shared__ double red[256];
    red[threadIdx.x] = acc; __syncthreads();
    for (int st = 128; st > 0; st >>= 1) {
        if (threadIdx.x < st) red[threadIdx.x] += red[threadIdx.x + st];
        __syncthreads();
    }
    double scale = 1.0 / fmax(sqrt(red[0]), 1e-12);
    for (int i = threadIdx.x; i < 4096; i += 256) dst[off + i] = src[off + i] * scale;
}

__global__ void norm64_f64_kernel(double* __restrict__ buf) {
    size_t off = (size_t)blockIdx.x * 4096;
    double acc = 0.0;
    for (int i = threadIdx.x; i < 4096; i += 256) { double v = buf[off + i]; acc += v * v; }
    __shared__ double red[256];
    red[threadIdx.x] = acc; __syncthreads();
    for (int st = 128; st > 0; st >>= 1) {
        if (threadIdx.x < st) red[threadIdx.x] += red[threadIdx.x + st];
        __syncthreads();
    }
    double scale = 1.0 / fmax(sqrt(red[0]), 1e-12);
    for (int i = threadIdx.x; i < 4096; i += 256) buf[off + i] *= scale;
}

__global__ void attnA64_kernel(const double* __restrict__ qn, const double* __restrict__ kn,
                               double* __restrict__ A) {
    int hh = blockIdx.x;
    int t = threadIdx.x;
    int c = t >> 3, d = t & 7;
    const double* q = qn + ((size_t)(hh * 32 + c)) * 4096;
    const double* k = kn + ((size_t)(hh * 8 + d)) * 4096;
    double acc = 0.0;
    for (int i = 0; i < 4096; ++i) acc += q[i] * k[i];
    __shared__ double S[32][8];
    S[c][d] = acc;
    __syncthreads();
    if (t < 32) {
        double mx = -1e300;
        for (int j = 0; j < 8; ++j) mx = fmax(mx, S[t][j]);
        double e[8], sum = 0.0;
        for (int j = 0; j < 8; ++j) { e[j] = exp(S[t][j] - mx); sum += e[j]; }
        double inv = 1.0 / sum;
        for (int j = 0; j < 8; ++j) A[((size_t)(hh * 32 + t)) * 8 + j] = e[j] * inv;
    }
}

__global__ void aout64_kernel(const double* __restrict__ A, const double* __restrict__ kn,
                              double* __restrict__ out) {
    int l = blockIdx.x * 256 + threadIdx.x;
    int ch = blockIdx.y;
    int hh = ch >> 5;
    const double* a = A + (size_t)ch * 8;
    const double* v = kn + ((size_t)(hh * 8)) * 4096 + l;
    double acc = 0.0;
    #pragma unroll
    for (int d = 0; d < 8; ++d) acc += a[d] * v[(size_t)d * 4096];
    out[(size_t)ch * 4096 + l] = acc;
}

__global__ void fm64_kernel(const double* __restrict__ in, const float* __restrict__ w,
                            double* __restrict__ out) {
    int l = blockIdx.x * 256 + threadIdx.x;
    int oc = blockIdx.y;
    const double* src = in + l;
    const float* wr = w + (size_t)oc * 192;
    double acc = 0.0;
    for (int ic = 0; ic < 192; ++ic) acc += (double)wr[ic] * src[(size_t)ic * 4096];
    out[(size_t)oc * 4096 + l] = acc;
}

__global__ void meanx64_kernel(const double* __restrict__ fm, double* __restrict__ m) {
    int x = blockIdx.x;
    double acc = 0.0;
    for (int t = threadIdx.x; t < 192 * 64; t += 256) {
        int c = t >> 6, y = t & 63;
        acc += fm[(size_t)c * 4096 + y * 64 + x];
    }
    __shared__ double red[256];
    red[threadIdx.x] = acc; __syncthreads();
    for (int st = 128; st > 0; st >>= 1) {
        if (threadIdx.x < st) red[threadIdx.x] += red[threadIdx.x + st];
        __syncthreads();
    }
    if (threadIdx.x == 0) m[x] = red[0] / (192.0 * 64.0);
}

__global__ void route64_kernel(const double* __restrict__ m, int* __restrict__ idx) {
    if (threadIdx.x != 0) return;
    double bins[12];
    for (int i = 0; i < 12; ++i) {
        int st = (i * 64) / 12;
        int en = ((i + 1) * 64 + 11) / 12;   // ceil
        double s = 0.0;
        for (int j = st; j < en; ++j) s += m[j];
        bins[i] = s / (double)(en - st);
    }
    bool used[12] = {};
    for (int s = 0; s < 4; ++s) {
        int best = 0; double bv = -1e300;
        for (int j = 0; j < 12; ++j)
            if (!used[j] && bins[j] > bv) { best = j; bv = bins[j]; }
        used[best] = true;
        idx[s] = best;
    }
}

// ================= f32 compute kernels =================

__global__ void rownorm_kernel(const float* __restrict__ src, float* __restrict__ dst) {
    size_t off = (size_t)blockIdx.x * 4096;
    const float* s = src + off;
    float acc = 0.f;
    for (int i = threadIdx.x; i < 4096; i += 256) { float v = s[i]; acc += v * v; }
    __shared__ float red[256];
    red[threadIdx.x] = acc; __syncthreads();
    for (int st = 128; st > 0; st >>= 1) {
        if (threadIdx.x < st) red[threadIdx.x] += red[threadIdx.x + st];
        __syncthreads();
    }
    float scale = 1.0f / fmaxf(sqrtf(red[0]), 1e-12f);
    float* d = dst + off;
    for (int i = threadIdx.x; i < 4096; i += 256) d[i] = s[i] * scale;
}

// Dense expert, register-tiled: 8 oc x 4 px per thread. grid (4, 24, 4), 256 thr.
template<int KK>
__global__ void dense_reg_kernel(const float* __restrict__ I, DPtrs dp,
                                 const int* __restrict__ idx, int slot,
                                 float* __restrict__ E) {
    int j = idx[slot];
    j = j < 0 ? 0 : (j > 11 ? 11 : j);
    if (j >= 6 || (1 + 2 * (j % 3)) != KK) return;
    constexpr int pad = (KK - 1) / 2;
    const float* wt = dp.wt[j];
    const float* bias = dp.bias[j];
    int tid = threadIdx.x;
    int tile = blockIdx.x, og8 = blockIdx.y, b = blockIdx.z;
    int p0 = tile * 1024 + tid;
    int x = tid & 63, y0 = p0 >> 6;
    float acc[8][4];
    #pragma unroll
    for (int u = 0; u < 8; ++u) {
        float bv = bias[og8 * 8 + u];
        #pragma unroll
        for (int k = 0; k < 4; ++k) acc[u][k] = bv;
    }
    const float* srcb = I + (size_t)b * 192 * 4096;
    for (int ky = 0; ky < KK; ++ky) {
        for (int kx = 0; kx < KK; ++kx) {
            const float* wp = wt + (((size_t)(ky * KK + kx)) * 24 + og8) * (192 * 8);
            int xx = x + kx - pad;
            bool xok = (xx >= 0 && xx < 64);
            int yyb = y0 + ky - pad;
            bool ok[4];
            #pragma unroll
            for (int k = 0; k < 4; ++k) {
                int yy = yyb + 4 * k;
                ok[k] = xok && (yy >= 0) && (yy < 64);
            }
            const float* sp = srcb + yyb * 64 + xx;
            for (int i = 0; i < 192; ++i) {
                float4 wA = *(const float4*)(wp + i * 8);
                float4 wB = *(const float4*)(wp + i * 8 + 4);
                float xv[4];
                #pragma unroll
                for (int k = 0; k < 4; ++k)
                    xv[k] = ok[k] ? sp[(size_t)i * 4096 + k * 256] : 0.f;
                #pragma unroll
                for (int k = 0; k < 4; ++k) {
                    acc[0][k] += wA.x * xv[k]; acc[1][k] += wA.y * xv[k];
                    acc[2][k] += wA.z * xv[k]; acc[3][k] += wA.w * xv[k];
                    acc[4][k] += wB.x * xv[k]; acc[5][k] += wB.y * xv[k];
                    acc[6][k] += wB.z * xv[k]; acc[7][k] += wB.w * xv[k];
                }
            }
        }
    }
    float* dst = E + ((size_t)(b * 192 + og8 * 8)) * 4096 + p0;
    #pragma unroll
    for (int u = 0; u < 8; ++u)
        #pragma unroll
        for (int k = 0; k < 4; ++k)
            dst[(size_t)u * 4096 + k * 256] = acc[u][k];
}

// Depthwise expert (unchanged). grid (16, 192, 4).
__global__ void expert_dw_kernel(const float* __restrict__ I, ExPtrs ep,
                                 const int* __restrict__ idx, int slot,
                                 float* __restrict__ E) {
    int j = idx[slot];
    j = j < 0 ? 0 : (j > 11 ? 11 : j);
    if (j < 6) return;
    int K = 1 + 2 * (j % 3), pad = j % 3;
    const float* w = ep.w[j];
    const float* bias = ep.b[j];
    int l = blockIdx.x * 256 + threadIdx.x;
    int ch = blockIdx.y, b = blockIdx.z;
    int y = l >> 6, x = l & 63;
    float acc = bias[ch];
    const float* src = I + ((size_t)(b * 192 + ch)) * 4096;
    for (int ky = 0; ky < K; ++ky)
        for (int kx = 0; kx < K; ++kx) {
            int yy = y + ky - pad, xx = x + kx - pad;
            if (yy >= 0 && yy < 64 && xx >= 0 && xx < 64)
                acc += w[((size_t)ch * K + ky) * K + kx] * src[yy * 64 + xx];
        }
    E[((size_t)(b * 192 + ch)) * 4096 + l] = acc;
}

// exout accumulate (3x3, slot-sliced over 768 ic). grid (4, 24, 4).
__global__ void exout_reg_kernel(const float* __restrict__ E, const float* __restrict__ wt,
                                 const float* __restrict__ bias, float* __restrict__ out,
                                 int slot) {
    int tid = threadIdx.x;
    int tile = blockIdx.x, og8 = blockIdx.y, b = blockIdx.z;
    int p0 = tile * 1024 + tid;
    int x = tid & 63, y0 = p0 >> 6;
    float* dst = out + ((size_t)(b * 192 + og8 * 8)) * 4096 + p0;
    float acc[8][4];
    #pragma unroll
    for (int u = 0; u < 8; ++u) {
        #pragma unroll
        for (int k = 0; k < 4; ++k)
            acc[u][k] = (slot == 0) ? bias[og8 * 8 + u] : dst[(size_t)u * 4096 + k * 256];
    }
    const float* srcb = E + (size_t)b * 192 * 4096;
    for (int ky = 0; ky < 3; ++ky) {
        for (int kx = 0; kx < 3; ++kx) {
            const float* wp = wt + ((((size_t)(ky * 3 + kx)) * 24 + og8) * 768 + slot * 192) * 8;
            int xx = x + kx - 1;
            bool xok = (xx >= 0 && xx < 64);
            int yyb = y0 + ky - 1;
            bool ok[4];
            #pragma unroll
            for (int k = 0; k < 4; ++k) {
                int yy = yyb + 4 * k;
                ok[k] = xok && (yy >= 0) && (yy < 64);
            }
            const float* sp = srcb + yyb * 64 + xx;
            for (int i = 0; i < 192; ++i) {
                float4 wA = *(const float4*)(wp + i * 8);
                float4 wB = *(const float4*)(wp + i * 8 + 4);
                float xv[4];
                #pragma unroll
                for (int k = 0; k < 4; ++k)
                    xv[k] = ok[k] ? sp[(size_t)i * 4096 + k * 256] : 0.f;
                #pragma unroll
                for (int k = 0; k < 4; ++k) {
                    acc[0][k] += wA.x * xv[k]; acc[1][k] += wA.y * xv[k];
                    acc[2][k] += wA.z * xv[k]; acc[3][k] += wA.w * xv[k];
                    acc[4][k] += wB.x * xv[k]; acc[5][k] += wB.y * xv[k];
                    acc[6][k] += wB.z * xv[k]; acc[7][k] += wB.w * xv[k];
                }
            }
        }
    }
    #pragma unroll
    for (int u = 0; u < 8; ++u)
        #pragma unroll
        for (int k = 0; k < 4; ++k)
            dst[(size_t)u * 4096 + k * 256] = acc[u][k];
}

// 1x1 conv via transposed weights (wt pre-offset for oc-half). grid (4, 24, 4).
__global__ void conv1x1_reg_kernel(const float* __restrict__ in, const float* __restrict__ wt,
                                   float* __restrict__ out) {
    int tid = threadIdx.x;
    int tile = blockIdx.x, og8 = blockIdx.y, b = blockIdx.z;
    int p0 = tile * 1024 + tid;
    float acc[8][4];
    #pragma unroll
    for (int u = 0; u < 8; ++u)
        #pragma unroll
        for (int k = 0; k < 4; ++k) acc[u][k] = 0.f;
    const float* src = in + (size_t)b * 192 * 4096 + p0;
    const float* wp = wt + (size_t)og8 * (192 * 8);
    for (int i = 0; i < 192; ++i) {
        float4 wA = *(const float4*)(wp + i * 8);
        float4 wB = *(const float4*)(wp + i * 8 + 4);
        float xv[4];
        #pragma unroll
        for (int k = 0; k < 4; ++k) xv[k] = src[(size_t)i * 4096 + k * 256];
        #pragma unroll
        for (int k = 0; k < 4; ++k) {
            acc[0][k] += wA.x * xv[k]; acc[1][k] += wA.y * xv[k];
            acc[2][k] += wA.z * xv[k]; acc[3][k] += wA.w * xv[k];
            acc[4][k] += wB.x * xv[k]; acc[5][k] += wB.y * xv[k];
            acc[6][k] += wB.z * xv[k]; acc[7][k] += wB.w * xv[k];
        }
    }
    float* dst = out + ((size_t)(b * 192 + og8 * 8)) * 4096 + p0;
    #pragma unroll
    for (int u = 0; u < 8; ++u)
        #pragma unroll
        for (int k = 0; k < 4; ++k)
            dst[(size_t)u * 4096 + k * 256] = acc[u][k];
}

// depthwise 3x3 pad1 no bias; w pre-offset. grid (16,192,4)
__global__ void dwconv_kernel(const float* __restrict__ in, const float* __restrict__ w,
                              float* __restrict__ out) {
    int l = blockIdx.x * 256 + threadIdx.x;
    int ch = blockIdx.y, b = blockIdx.z;
    int y = l >> 6, x = l & 63;
    const float* src = in + ((size_t)(b * 192 + ch)) * 4096;
    const float* wk = w + ch * 9;
    float acc = 0.f;
    #pragma unroll
    for (int ky = 0; ky < 3; ++ky)
        #pragma unroll
        for (int kx = 0; kx < 3; ++kx) {
            int yy = y + ky - 1, xx = x + kx - 1;
            if (yy >= 0 && yy < 64 && xx >= 0 && xx < 64)
                acc += wk[ky * 3 + kx] * src[yy * 64 + xx];
        }
    out[((size_t)(b * 192 + ch)) * 4096 + l] = acc;
}

// Final attention logits+softmax, one block per q-row. grid (768), 256 thr.
__global__ void attnF_row_kernel(const float* __restrict__ qn, const float* __restrict__ kn,
                                 const float* __restrict__ temp, float* __restrict__ AF) {
    int row = blockIdx.x;            // ((b*6+hh)*32 + c)
    int hh = (row >> 5) % 6, b = row / 192;
    int tid = threadIdx.x;
    const float* q = qn + ((size_t)(b * 192) + (row % 192)) * 4096;
    const float* kb = kn + ((size_t)(b * 192 + hh * 32)) * 4096;
    float acc[32];
    #pragma unroll
    for (int d = 0; d < 32; ++d) acc[d] = 0.f;
    for (int i = tid; i < 4096; i += 256) {
        float qv = q[i];
        #pragma unroll
        for (int d = 0; d < 32; ++d) acc[d] += qv * kb[(size_t)d * 4096 + i];
    }
    #pragma unroll
    for (int d = 0; d < 32; ++d) {
        acc[d] += __shfl_xor(acc[d], 32);
        acc[d] += __shfl_xor(acc[d], 16);
        acc[d] += __shfl_xor(acc[d], 8);
        acc[d] += __shfl_xor(acc[d], 4);
        acc[d] += __shfl_xor(acc[d], 2);
        acc[d] += __shfl_xor(acc[d], 1);
    }
    __shared__ float red[4][32];
    int wid = tid >> 6, lane = tid & 63;
    if (lane == 0) {
        #pragma unroll
        for (int d = 0; d < 32; ++d) red[wid][d] = acc[d];
    }
    __syncthreads();
    if (tid < 32) {
        float s = red[0][tid] + red[1][tid] + red[2][tid] + red[3][tid];
        s *= temp[hh];
        float mx = s;
        mx = fmaxf(mx, __shfl_xor(mx, 16));
        mx = fmaxf(mx, __shfl_xor(mx, 8));
        mx = fmaxf(mx, __shfl_xor(mx, 4));
        mx = fmaxf(mx, __shfl_xor(mx, 2));
        mx = fmaxf(mx, __shfl_xor(mx, 1));
        float e = expf(s - mx);
        float sum = e;
        sum += __shfl_xor(sum, 16);
        sum += __shfl_xor(sum, 8);
        sum += __shfl_xor(sum, 4);
        sum += __shfl_xor(sum, 2);
        sum += __shfl_xor(sum, 1);
        AF[(size_t)row * 32 + tid] = e / sum;
    }
}

__global__ void attnF_out_kernel(const float* __restrict__ AF, const float* __restrict__ v,
                                 float* __restrict__ out) {
    int l = blockIdx.x * 256 + threadIdx.x;
    int ch = blockIdx.y, b = blockIdx.z;
    int hh = ch >> 5, c = ch & 31;
    const float* a = AF + ((size_t)((b * 6 + hh) * 32 + c)) * 32;
    const float* vp = v + ((size_t)(b * 192 + hh * 32)) * 4096 + l;
    float acc = 0.f;
    #pragma unroll
    for (int d = 0; d < 32; ++d) acc += a[d] * vp[(size_t)d * 4096];
    out[((size_t)(b * 192 + ch)) * 4096 + l] = acc;
}

// ---------------- launch ----------------
extern "C" void kernel_launch(void* const* d_in, const int* in_sizes, int n_in,
                              void* d_out, int out_size, void* d_ws, size_t ws_size,
                              hipStream_t stream) {
    const float* I    = (const float*)d_in[0];
    const float* T    = (const float*)d_in[1];
    const float* temp = (const float*)d_in[2];
    const float* ca1  = (const float*)d_in[3];
    const float* exow = (const float*)d_in[4];
    const float* exob = (const float*)d_in[5];
    const float* kvw  = (const float*)d_in[6];
    const float* kvdw = (const float*)d_in[7];
    const float* qdw  = (const float*)d_in[8];
    const float* projw= (const float*)d_in[9];
    ExPtrs ep;
    for (int j = 0; j < 12; ++j) {
        ep.w[j] = (const float*)d_in[10 + 2 * j];
        ep.b[j] = (const float*)d_in[11 + 2 * j];
    }

    // Arena (floats): AF | idxb | R0 | R1 | R2 | f64 smalls | transposed weights
    float* ws   = (float*)d_ws;
    float* AF   = ws;                 // 24576
    int*   idxb = (int*)(ws + 24576); // 4
    float* R0   = ws + 32768;
    float* R1   = R0 + 3145728;
    float* R2   = R1 + 3145728;
    double* dbase   = (double*)(R2 + 3145728);   // byte offset divisible by 8
    double* A64     = dbase;                     // 1536
    double* m64     = dbase + 1536;              // 64
    double* xpool64 = (double*)R0;               // 196608 (f64) within R0
    double* qn64    = xpool64 + 196608 * 2;      // reuse R0 tail? -> layout below
    // f64 stage-A buffers inside R0/R1 (dead before back half):
    //   xpool64: R0[0 .. 393216 floats)   (196608 f64)
    //   qn64   : R0[393216 .. 1966080)    (786432 f64)
    qn64 = (double*)(R0 + 393216);
    double* aout64  = (double*)R1;               // 786432 f64 = 1572864 floats
    double* fm64    = (double*)(R1 + 1572864);   // 786432 f64
    // transposed weights after f64 smalls (3200 floats)
    float* wtbase = R2 + 3145728 + 3200;
    size_t wtoff[6] = {0, 36864, 368640, 1290240, 1327104, 1658880};
    float* wtexo  = wtbase + 2580480;
    float* wtkv   = wtexo + 1327104;
    float* wtproj = wtkv + 73728;
    DPtrs dp;
    for (int j = 0; j < 6; ++j) { dp.wt[j] = wtbase + wtoff[j]; dp.bias[j] = ep.b[j]; }
    float* out  = (float*)d_out;

    dim3 g(16, 192, 4), gr(4, 24, 4);

    // ---- weight transposes (independent of everything) ----
    for (int j = 0; j < 6; ++j) {
        int KK = 1 + 2 * (j % 3);
        wtr_kernel<<<1024, 256, 0, stream>>>(ep.w[j], wtbase + wtoff[j], 24, 192, KK);
    }
    wtr_kernel<<<1024, 256, 0, stream>>>(exow, wtexo, 24, 768, 3);
    wtr_kernel<<<1024, 256, 0, stream>>>(kvw, wtkv, 48, 192, 1);
    wtr_kernel<<<1024, 256, 0, stream>>>(projw, wtproj, 24, 192, 1);

    // ---- Routing chain (b=0, f64) ----
    pool64_kernel<<<48, 256, 0, stream>>>(T, xpool64);
    norm64_f32_kernel<<<192, 256, 0, stream>>>(I, qn64);
    norm64_f64_kernel<<<48, 256, 0, stream>>>(xpool64);
    attnA64_kernel<<<6, 256, 0, stream>>>(qn64, xpool64, A64);
    aout64_kernel<<<dim3(16, 192), 256, 0, stream>>>(A64, xpool64, aout64);
    fm64_kernel<<<dim3(16, 192), 256, 0, stream>>>(aout64, ca1, fm64);
    meanx64_kernel<<<64, 256, 0, stream>>>(fm64, m64);
    route64_kernel<<<1, 64, 0, stream>>>(m64, idxb);

    // ---- Experts: E=R2, fmap2 accumulates in R1 ----
    for (int s = 0; s < 4; ++s) {
        dense_reg_kernel<1><<<gr, 256, 0, stream>>>(I, dp, idxb, s, R2);
        dense_reg_kernel<3><<<gr, 256, 0, stream>>>(I, dp, idxb, s, R2);
        dense_reg_kernel<5><<<gr, 256, 0, stream>>>(I, dp, idxb, s, R2);
        expert_dw_kernel<<<g, 256, 0, stream>>>(I, ep, idxb, s, R2);
        exout_reg_kernel<<<gr, 256, 0, stream>>>(R2, wtexo, exob, R1, s);
    }

    // ---- kv k-half ----
    conv1x1_reg_kernel<<<gr, 256, 0, stream>>>(R1, wtkv, R0);
    dwconv_kernel<<<g, 256, 0, stream>>>(R0, kvdw, R2);
    rownorm_kernel<<<768, 256, 0, stream>>>(R2, R2);          // kn
    // ---- q ----
    dwconv_kernel<<<g, 256, 0, stream>>>(R1, qdw, R0);
    rownorm_kernel<<<768, 256, 0, stream>>>(R0, R0);          // qn
    attnF_row_kernel<<<768, 256, 0, stream>>>(R0, R2, temp, AF);
    // ---- kv v-half ----
    conv1x1_reg_kernel<<<gr, 256, 0, stream>>>(R1, wtkv + 36864, R0);
    dwconv_kernel<<<g, 256, 0, stream>>>(R0, kvdw + 192 * 9, R2);  // v

    attnF_out_kernel<<<g, 256, 0, stream>>>(AF, R2, R1);
    conv1x1_reg_kernel<<<gr, 256, 0, stream>>>(R1, wtproj, out);
}

// Round 10
// 2041.508 us; speedup vs baseline: 2.3522x; 1.9435x over previous
//
#include <hip/hip_runtime.h>
#include <math.h>

// B=4, DIM=192, H=W=64, L=4096, HEADS=6. f32 buffers; f64 routing chain (b=0).
// Convs: sliding-window register-tiled implicit GEMM, 4oc x 4px/thread,
// padded inputs (no bounds checks), ic-outer/tap-inner for window reuse,
// weights pre-transposed to [og][ic][kk][4] (scalar float4 taps).

struct ExPtrs { const float* w[12]; const float* b[12]; };
struct DPtrs  { const float* wt[6]; const float* bias[6]; };

__device__ __forceinline__ void fma4(float4& a, float s, const float4& v) {
    a.x = fmaf(s, v.x, a.x); a.y = fmaf(s, v.y, a.y);
    a.z = fmaf(s, v.z, a.z); a.w = fmaf(s, v.w, a.w);
}

// ---------------- helpers ----------------
__global__ void zero_kernel(float* __restrict__ p, int n) {
    for (int i = blockIdx.x * 256 + threadIdx.x; i < n; i += gridDim.x * 256) p[i] = 0.f;
}

// I [4,192,64,64] -> Ipad [4,192,68,68] with 2-ring zero pad
__global__ void padfill_kernel(const float* __restrict__ I, float* __restrict__ Ipad) {
    const int n = 4 * 192 * 4624;
    for (int o = blockIdx.x * 256 + threadIdx.x; o < n; o += gridDim.x * 256) {
        int xx = o % 68;
        int t = o / 68;
        int yy = t % 68;
        int t2 = t / 68;
        int ch = t2 % 192;
        int b = t2 / 192;
        float v = 0.f;
        if (yy >= 2 && yy < 66 && xx >= 2 && xx < 66)
            v = I[(((size_t)(b * 192 + ch)) << 12) + (yy - 2) * 64 + (xx - 2)];
        Ipad[o] = v;
    }
}

// w[(og*4+u)*IC+ic][kk] -> wt[((og*IC+ic)*K2+kk)*4+u]
__global__ void wtr_kernel(const float* __restrict__ w, float* __restrict__ wt,
                           int OCg, int IC, int K2) {
    int n = OCg * IC * K2 * 4;
    for (int o = blockIdx.x * 256 + threadIdx.x; o < n; o += gridDim.x * 256) {
        int u = o & 3;
        int t = o >> 2;
        int kk = t % K2;
        int t2 = t / K2;
        int ic = t2 % IC;
        int og = t2 / IC;
        wt[o] = w[(((size_t)(og * 4 + u)) * IC + ic) * K2 + kk];
    }
}

// ================= routing chain, b=0, all f64 (unchanged) =================

__global__ void pool64_kernel(const float* __restrict__ T, double* __restrict__ xp) {
    int j = blockIdx.x;
    for (int l = threadIdx.x; l < 4096; l += 256) {
        const float* t = T + ((size_t)(4 * j)) * 4096 + l;
        double s = (double)t[0] + (double)t[4096] + (double)t[2 * 4096] + (double)t[3 * 4096];
        xp[(size_t)j * 4096 + l] = 0.25 * s;
    }
}

__global__ void norm64_f32_kernel(const float* __restrict__ src, double* __restrict__ dst) {
    size_t off = (size_t)blockIdx.x * 4096;
    double acc = 0.0;
    for (int i = threadIdx.x; i < 4096; i += 256) { double v = src[off + i]; acc += v * v; }
    __shared__ double red[256];
    red[threadIdx.x] = acc; __syncthreads();
    for (int st = 128; st > 0; st >>= 1) {
        if (threadIdx.x < st) red[threadIdx.x] += red[threadIdx.x + st];
        __syncthreads();
    }
    double scale = 1.0 / fmax(sqrt(red[0]), 1e-12);
    for (int i = threadIdx.x; i < 4096; i += 256) dst[off + i] = src[off + i] * scale;
}

__global__ void norm64_f64_kernel(double* __restrict__ buf) {
    size_t off = (size_t)blockIdx.x * 4096;
    double acc = 0.0;
    for (int i = threadIdx.x; i < 4096; i += 256) { double v = buf[off + i]; acc += v * v; }
    __shared__ double red[256];
    red[threadIdx.x] = acc; __syncthreads();
    for (int st = 128; st > 0; st >>= 1) {
        if (threadIdx.x < st) red[threadIdx.x] += red[threadIdx.x + st];
        __syncthreads();
    }
    double scale = 1.0 / fmax(sqrt(red[0]), 1e-12);
    for (int i = threadIdx.x; i < 4096; i += 256) buf[off + i] *= scale;
}

__global__ void attnA64_kernel(const double* __restrict__ qn, const double* __restrict__ kn,
                               double* __restrict__ A) {
    int hh = blockIdx.x;
    int t = threadIdx.x;
    int c = t >> 3, d = t & 7;
    const double* q = qn + ((size_t)(hh * 32 + c)) * 4096;
    const double* k = kn + ((size_t)(hh * 8 + d)) * 4096;
    double acc = 0.0;
    for (int i = 0; i < 4096; ++i) acc += q[i] * k[i];
    __shared__ double S[32][8];
    S[c][d] = acc;
    __syncthreads();
    if (t < 32) {
        double mx = -1e300;
        for (int j = 0; j < 8; ++j) mx = fmax(mx, S[t][j]);
        double e[8], sum = 0.0;
        for (int j = 0; j < 8; ++j) { e[j] = exp(S[t][j] - mx); sum += e[j]; }
        double inv = 1.0 / sum;
        for (int j = 0; j < 8; ++j) A[((size_t)(hh * 32 + t)) * 8 + j] = e[j] * inv;
    }
}

__global__ void aout64_kernel(const double* __restrict__ A, const double* __restrict__ kn,
                              double* __restrict__ out) {
    int l = blockIdx.x * 256 + threadIdx.x;
    int ch = blockIdx.y;
    int hh = ch >> 5;
    const double* a = A + (size_t)ch * 8;
    const double* v = kn + ((size_t)(hh * 8)) * 4096 + l;
    double acc = 0.0;
    #pragma unroll
    for (int d = 0; d < 8; ++d) acc += a[d] * v[(size_t)d * 4096];
    out[(size_t)ch * 4096 + l] = acc;
}

__global__ void fm64_kernel(const double* __restrict__ in, const float* __restrict__ w,
                            double* __restrict__ out) {
    int l = blockIdx.x * 256 + threadIdx.x;
    int oc = blockIdx.y;
    const double* src = in + l;
    const float* wr = w + (size_t)oc * 192;
    double acc = 0.0;
    for (int ic = 0; ic < 192; ++ic) acc += (double)wr[ic] * src[(size_t)ic * 4096];
    out[(size_t)oc * 4096 + l] = acc;
}

__global__ void meanx64_kernel(const double* __restrict__ fm, double* __restrict__ m) {
    int x = blockIdx.x;
    double acc = 0.0;
    for (int t = threadIdx.x; t < 192 * 64; t += 256) {
        int c = t >> 6, y = t & 63;
        acc += fm[(size_t)c * 4096 + y * 64 + x];
    }
    __shared__ double red[256];
    red[threadIdx.x] = acc; __syncthreads();
    for (int st = 128; st > 0; st >>= 1) {
        if (threadIdx.x < st) red[threadIdx.x] += red[threadIdx.x + st];
        __syncthreads();
    }
    if (threadIdx.x == 0) m[x] = red[0] / (192.0 * 64.0);
}

__global__ void route64_kernel(const double* __restrict__ m, int* __restrict__ idx) {
    if (threadIdx.x != 0) return;
    double bins[12];
    for (int i = 0; i < 12; ++i) {
        int st = (i * 64) / 12;
        int en = ((i + 1) * 64 + 11) / 12;   // ceil
        double s = 0.0;
        for (int j = st; j < en; ++j) s += m[j];
        bins[i] = s / (double)(en - st);
    }
    bool used[12] = {};
    for (int s = 0; s < 4; ++s) {
        int best = 0; double bv = -1e300;
        for (int j = 0; j < 12; ++j)
            if (!used[j] && bins[j] > bv) { best = j; bv = bins[j]; }
        used[best] = true;
        idx[s] = best;
    }
}

// ================= f32 compute kernels =================

__global__ void rownorm_kernel(const float* __restrict__ src, float* __restrict__ dst) {
    size_t off = (size_t)blockIdx.x * 4096;
    const float* s = src + off;
    float acc = 0.f;
    for (int i = threadIdx.x; i < 4096; i += 256) { float v = s[i]; acc += v * v; }
    __shared__ float red[256];
    red[threadIdx.x] = acc; __syncthreads();
    for (int st = 128; st > 0; st >>= 1) {
        if (threadIdx.x < st) red[threadIdx.x] += red[threadIdx.x + st];
        __syncthreads();
    }
    float scale = 1.0f / fmaxf(sqrtf(red[0]), 1e-12f);
    float* d = dst + off;
    for (int i = threadIdx.x; i < 4096; i += 256) d[i] = s[i] * scale;
}

// Dense expert, sliding window. grid (4, 48, 4), 256 thr.
template<int KK>
__global__ void dense_sw_kernel(const float* __restrict__ Ipad, DPtrs dp,
                                const int* __restrict__ idx, int slot,
                                float* __restrict__ Epad) {
    int j = idx[slot];
    j = j < 0 ? 0 : (j > 11 ? 11 : j);
    if (j >= 6 || (1 + 2 * (j % 3)) != KK) return;
    constexpr int P = (KK - 1) / 2;
    constexpr int K2 = KK * KK;
    const float* wt = dp.wt[j];
    const float* bias = dp.bias[j];
    int tid = threadIdx.x;
    int xq = tid & 15, ry = tid >> 4;
    int tile = blockIdx.x, og = blockIdx.y, b = blockIdx.z;
    int y = tile * 16 + ry, x0 = xq * 4;
    float4 acc[4];
    #pragma unroll
    for (int u = 0; u < 4; ++u) {
        float bv = bias[og * 4 + u];
        acc[u] = make_float4(bv, bv, bv, bv);
    }
    const float* srcb = Ipad + (size_t)b * 192 * 4624 + (y - P + 2) * 68 + (x0 - P + 2);
    const float* wp = wt + (size_t)og * 192 * K2 * 4;
    for (int ic = 0; ic < 192; ++ic) {
        const float* rp = srcb + (size_t)ic * 4624;
        const float* wq = wp + (size_t)ic * K2 * 4;
        #pragma unroll
        for (int ky = 0; ky < KK; ++ky) {
            float win[8];
            float4 A = *(const float4*)(rp + ky * 68);
            win[0] = A.x; win[1] = A.y; win[2] = A.z; win[3] = A.w;
            if (KK > 1) {
                float4 Bv = *(const float4*)(rp + ky * 68 + 4);
                win[4] = Bv.x; win[5] = Bv.y; win[6] = Bv.z; win[7] = Bv.w;
            } else {
                win[4] = win[5] = win[6] = win[7] = 0.f;
            }
            #pragma unroll
            for (int kx = 0; kx < KK; ++kx) {
                float4 wv = *(const float4*)(wq + (ky * KK + kx) * 4);
                float4 xv = make_float4(win[kx], win[kx + 1], win[kx + 2], win[kx + 3]);
                fma4(acc[0], wv.x, xv);
                fma4(acc[1], wv.y, xv);
                fma4(acc[2], wv.z, xv);
                fma4(acc[3], wv.w, xv);
            }
        }
    }
    float* dst = Epad + ((size_t)(b * 192 + og * 4)) * 4356 + (y + 1) * 66 + (x0 + 1);
    #pragma unroll
    for (int u = 0; u < 4; ++u)
        *(float4*)(dst + (size_t)u * 4356) = acc[u];
}

// Depthwise expert -> Epad. grid (16, 192, 4).
__global__ void expert_dw_kernel(const float* __restrict__ I, ExPtrs ep,
                                 const int* __restrict__ idx, int slot,
                                 float* __restrict__ Epad) {
    int j = idx[slot];
    j = j < 0 ? 0 : (j > 11 ? 11 : j);
    if (j < 6) return;
    int K = 1 + 2 * (j % 3), pad = j % 3;
    const float* w = ep.w[j];
    const float* bias = ep.b[j];
    int l = blockIdx.x * 256 + threadIdx.x;
    int ch = blockIdx.y, b = blockIdx.z;
    int y = l >> 6, x = l & 63;
    float acc = bias[ch];
    const float* src = I + ((size_t)(b * 192 + ch)) * 4096;
    for (int ky = 0; ky < K; ++ky)
        for (int kx = 0; kx < K; ++kx) {
            int yy = y + ky - pad, xx = x + kx - pad;
            if (yy >= 0 && yy < 64 && xx >= 0 && xx < 64)
                acc += w[((size_t)ch * K + ky) * K + kx] * src[yy * 64 + xx];
        }
    Epad[((size_t)(b * 192 + ch)) * 4356 + (y + 1) * 66 + (x + 1)] = acc;
}

// exout slot accumulate (3x3 over padded E). grid (4, 48, 4).
__global__ void exout_sw_kernel(const float* __restrict__ Epad, const float* __restrict__ wt,
                                const float* __restrict__ bias, float* __restrict__ out,
                                int slot) {
    int tid = threadIdx.x;
    int xq = tid & 15, ry = tid >> 4;
    int tile = blockIdx.x, og = blockIdx.y, b = blockIdx.z;
    int y = tile * 16 + ry, x0 = xq * 4;
    float* dst = out + ((size_t)(b * 192 + og * 4)) * 4096 + y * 64 + x0;
    float4 acc[4];
    #pragma unroll
    for (int u = 0; u < 4; ++u) {
        if (slot == 0) { float bv = bias[og * 4 + u]; acc[u] = make_float4(bv, bv, bv, bv); }
        else acc[u] = *(const float4*)(dst + (size_t)u * 4096);
    }
    const float* srcb = Epad + (size_t)b * 192 * 4356 + y * 66 + x0;
    const float* wp = wt + ((size_t)og * 768 + slot * 192) * 9 * 4;
    for (int ic = 0; ic < 192; ++ic) {
        const float* rp = srcb + (size_t)ic * 4356;
        const float* wq = wp + (size_t)ic * 36;
        #pragma unroll
        for (int ky = 0; ky < 3; ++ky) {
            float4 A = *(const float4*)(rp + ky * 66);
            float4 Bv = *(const float4*)(rp + ky * 66 + 4);
            float win[8] = {A.x, A.y, A.z, A.w, Bv.x, Bv.y, Bv.z, Bv.w};
            #pragma unroll
            for (int kx = 0; kx < 3; ++kx) {
                float4 wv = *(const float4*)(wq + (ky * 3 + kx) * 4);
                float4 xv = make_float4(win[kx], win[kx + 1], win[kx + 2], win[kx + 3]);
                fma4(acc[0], wv.x, xv);
                fma4(acc[1], wv.y, xv);
                fma4(acc[2], wv.z, xv);
                fma4(acc[3], wv.w, xv);
            }
        }
    }
    #pragma unroll
    for (int u = 0; u < 4; ++u)
        *(float4*)(dst + (size_t)u * 4096) = acc[u];
}

// 1x1 conv, plain in/out, wt pre-offset. grid (4, 48, 4).
__global__ void conv1x1_sw_kernel(const float* __restrict__ in, const float* __restrict__ wt,
                                  float* __restrict__ out) {
    int tid = threadIdx.x;
    int xq = tid & 15, ry = tid >> 4;
    int tile = blockIdx.x, og = blockIdx.y, b = blockIdx.z;
    int p0 = tile * 1024 + ry * 64 + xq * 4;
    float4 acc[4] = {};
    const float* src = in + (size_t)b * 192 * 4096 + p0;
    const float* wp = wt + (size_t)og * 192 * 4;
    for (int ic = 0; ic < 192; ++ic) {
        float4 xv = *(const float4*)(src + (size_t)ic * 4096);
        float4 wv = *(const float4*)(wp + ic * 4);
        fma4(acc[0], wv.x, xv);
        fma4(acc[1], wv.y, xv);
        fma4(acc[2], wv.z, xv);
        fma4(acc[3], wv.w, xv);
    }
    float* dst = out + ((size_t)(b * 192 + og * 4)) * 4096 + p0;
    #pragma unroll
    for (int u = 0; u < 4; ++u)
        *(float4*)(dst + (size_t)u * 4096) = acc[u];
}

// depthwise 3x3 pad1 no bias; plain in/out; w pre-offset. grid (16,192,4)
__global__ void dwconv_kernel(const float* __restrict__ in, const float* __restrict__ w,
                              float* __restrict__ out) {
    int l = blockIdx.x * 256 + threadIdx.x;
    int ch = blockIdx.y, b = blockIdx.z;
    int y = l >> 6, x = l & 63;
    const float* src = in + ((size_t)(b * 192 + ch)) * 4096;
    const float* wk = w + ch * 9;
    float acc = 0.f;
    #pragma unroll
    for (int ky = 0; ky < 3; ++ky)
        #pragma unroll
        for (int kx = 0; kx < 3; ++kx) {
            int yy = y + ky - 1, xx = x + kx - 1;
            if (yy >= 0 && yy < 64 && xx >= 0 && xx < 64)
                acc += wk[ky * 3 + kx] * src[yy * 64 + xx];
        }
    out[((size_t)(b * 192 + ch)) * 4096 + l] = acc;
}

// Final attention logits+softmax, one block per q-row. grid (768), 256 thr.
__global__ void attnF_row_kernel(const float* __restrict__ qn, const float* __restrict__ kn,
                                 const float* __restrict__ temp, float* __restrict__ AF) {
    int row = blockIdx.x;            // ((b*6+hh)*32 + c)
    int hh = (row >> 5) % 6, b = row / 192;
    int tid = threadIdx.x;
    const float* q = qn + ((size_t)(b * 192) + (row % 192)) * 4096;
    const float* kb = kn + ((size_t)(b * 192 + hh * 32)) * 4096;
    float acc[32];
    #pragma unroll
    for (int d = 0; d < 32; ++d) acc[d] = 0.f;
    for (int i = tid; i < 4096; i += 256) {
        float qv = q[i];
        #pragma unroll
        for (int d = 0; d < 32; ++d) acc[d] += qv * kb[(size_t)d * 4096 + i];
    }
    #pragma unroll
    for (int d = 0; d < 32; ++d) {
        acc[d] += __shfl_xor(acc[d], 32);
        acc[d] += __shfl_xor(acc[d], 16);
        acc[d] += __shfl_xor(acc[d], 8);
        acc[d] += __shfl_xor(acc[d], 4);
        acc[d] += __shfl_xor(acc[d], 2);
        acc[d] += __shfl_xor(acc[d], 1);
    }
    __shared__ float red[4][32];
    int wid = tid >> 6, lane = tid & 63;
    if (lane == 0) {
        #pragma unroll
        for (int d = 0; d < 32; ++d) red[wid][d] = acc[d];
    }
    __syncthreads();
    if (tid < 32) {
        float s = red[0][tid] + red[1][tid] + red[2][tid] + red[3][tid];
        s *= temp[hh];
        float mx = s;
        mx = fmaxf(mx, __shfl_xor(mx, 16));
        mx = fmaxf(mx, __shfl_xor(mx, 8));
        mx = fmaxf(mx, __shfl_xor(mx, 4));
        mx = fmaxf(mx, __shfl_xor(mx, 2));
        mx = fmaxf(mx, __shfl_xor(mx, 1));
        float e = expf(s - mx);
        float sum = e;
        sum += __shfl_xor(sum, 16);
        sum += __shfl_xor(sum, 8);
        sum += __shfl_xor(sum, 4);
        sum += __shfl_xor(sum, 2);
        sum += __shfl_xor(sum, 1);
        AF[(size_t)row * 32 + tid] = e / sum;
    }
}

__global__ void attnF_out_kernel(const float* __restrict__ AF, const float* __restrict__ v,
                                 float* __restrict__ out) {
    int l = blockIdx.x * 256 + threadIdx.x;
    int ch = blockIdx.y, b = blockIdx.z;
    int hh = ch >> 5, c = ch & 31;
    const float* a = AF + ((size_t)((b * 6 + hh) * 32 + c)) * 32;
    const float* vp = v + ((size_t)(b * 192 + hh * 32)) * 4096 + l;
    float acc = 0.f;
    #pragma unroll
    for (int d = 0; d < 32; ++d) acc += a[d] * vp[(size_t)d * 4096];
    out[((size_t)(b * 192 + ch)) * 4096 + l] = acc;
}

// ---------------- launch ----------------
extern "C" void kernel_launch(void* const* d_in, const int* in_sizes, int n_in,
                              void* d_out, int out_size, void* d_ws, size_t ws_size,
                              hipStream_t stream) {
    const float* I    = (const float*)d_in[0];
    const float* T    = (const float*)d_in[1];
    const float* temp = (const float*)d_in[2];
    const float* ca1  = (const float*)d_in[3];
    const float* exow = (const float*)d_in[4];
    const float* exob = (const float*)d_in[5];
    const float* kvw  = (const float*)d_in[6];
    const float* kvdw = (const float*)d_in[7];
    const float* qdw  = (const float*)d_in[8];
    const float* projw= (const float*)d_in[9];
    ExPtrs ep;
    for (int j = 0; j < 12; ++j) {
        ep.w[j] = (const float*)d_in[10 + 2 * j];
        ep.b[j] = (const float*)d_in[11 + 2 * j];
    }

    // Arena (floats), total ~69 MB:
    float* ws   = (float*)d_ws;
    float* AF   = ws;                       // 24576
    int*   idxb = (int*)(ws + 24576);       // 4
    float* R0   = ws + 32768;               // 3,145,728
    float* R1   = R0 + 3145728;             // 3,145,728
    float* Ipad = R1 + 3145728;             // 3,551,232 (later: KN)
    float* Epad = Ipad + 3551232;           // 3,345,408 (later: V)
    double* dsm = (double*)(Epad + 3345408);
    double* A64 = dsm;                      // 1536
    double* m64 = dsm + 1536;               // 64
    float* wtd  = (float*)(dsm + 1600);     // dense wt: 2,580,480
    size_t wtoff[6] = {0, 36864, 368640, 1290240, 1327104, 1658880};
    float* wtexo  = wtd + 2580480;          // 1,327,104
    float* wtkv   = wtexo + 1327104;        // 73,728
    float* wtproj = wtkv + 73728;           // 36,864
    // f64 stage-A buffers inside R0/R1 (dead before back half):
    double* xpool64 = (double*)R0;               // 196,608 d
    double* qn64    = (double*)(R0 + 393216);    // 786,432 d
    double* aout64  = (double*)R1;               // 786,432 d
    double* fm64    = (double*)(R1 + 1572864);   // 786,432 d
    float* KN = Ipad;
    float* V  = Epad;
    DPtrs dp;
    for (int j = 0; j < 6; ++j) { dp.wt[j] = wtd + wtoff[j]; dp.bias[j] = ep.b[j]; }
    float* out  = (float*)d_out;

    dim3 g(16, 192, 4), gs(4, 48, 4);

    // ---- weight transposes + input padding ----
    for (int j = 0; j < 6; ++j) {
        int KK = 1 + 2 * (j % 3);
        wtr_kernel<<<512, 256, 0, stream>>>(ep.w[j], wtd + wtoff[j], 48, 192, KK * KK);
    }
    wtr_kernel<<<1024, 256, 0, stream>>>(exow, wtexo, 48, 768, 9);
    wtr_kernel<<<256, 256, 0, stream>>>(kvw, wtkv, 96, 192, 1);
    wtr_kernel<<<256, 256, 0, stream>>>(projw, wtproj, 48, 192, 1);
    padfill_kernel<<<2048, 256, 0, stream>>>(I, Ipad);
    zero_kernel<<<2048, 256, 0, stream>>>(Epad, 3345408);

    // ---- Routing chain (b=0, f64) ----
    pool64_kernel<<<48, 256, 0, stream>>>(T, xpool64);
    norm64_f32_kernel<<<192, 256, 0, stream>>>(I, qn64);
    norm64_f64_kernel<<<48, 256, 0, stream>>>(xpool64);
    attnA64_kernel<<<6, 256, 0, stream>>>(qn64, xpool64, A64);
    aout64_kernel<<<dim3(16, 192), 256, 0, stream>>>(A64, xpool64, aout64);
    fm64_kernel<<<dim3(16, 192), 256, 0, stream>>>(aout64, ca1, fm64);
    meanx64_kernel<<<64, 256, 0, stream>>>(fm64, m64);
    route64_kernel<<<1, 64, 0, stream>>>(m64, idxb);

    // ---- Experts: E in Epad, fmap2 accumulates in R1 ----
    for (int s = 0; s < 4; ++s) {
        dense_sw_kernel<1><<<gs, 256, 0, stream>>>(Ipad, dp, idxb, s, Epad);
        dense_sw_kernel<3><<<gs, 256, 0, stream>>>(Ipad, dp, idxb, s, Epad);
        dense_sw_kernel<5><<<gs, 256, 0, stream>>>(Ipad, dp, idxb, s, Epad);
        expert_dw_kernel<<<g, 256, 0, stream>>>(I, ep, idxb, s, Epad);
        exout_sw_kernel<<<gs, 256, 0, stream>>>(Epad, wtexo, exob, R1, s);
    }

    // ---- kv k-half (Ipad dead -> KN) ----
    conv1x1_sw_kernel<<<gs, 256, 0, stream>>>(R1, wtkv, R0);
    dwconv_kernel<<<g, 256, 0, stream>>>(R0, kvdw, KN);
    rownorm_kernel<<<768, 256, 0, stream>>>(KN, KN);             // kn
    // ---- q ----
    dwconv_kernel<<<g, 256, 0, stream>>>(R1, qdw, R0);
    rownorm_kernel<<<768, 256, 0, stream>>>(R0, R0);             // qn
    attnF_row_kernel<<<768, 256, 0, stream>>>(R0, KN, temp, AF);
    // ---- kv v-half (Epad dead -> V) ----
    conv1x1_sw_kernel<<<gs, 256, 0, stream>>>(R1, wtkv + 36864, R0);
    dwconv_kernel<<<g, 256, 0, stream>>>(R0, kvdw + 192 * 9, V);

    attnF_out_kernel<<<g, 256, 0, stream>>>(AF, V, R0);
    conv1x1_sw_kernel<<<gs, 256, 0, stream>>>(R0, wtproj, out);
}